// Round 7
// baseline (235.905 us; speedup 1.0000x reference)
//
#include <hip/hip_runtime.h>
#include <cstdint>
#include <cstddef>

namespace {

constexpr int Bn   = 8;
constexpr int Cc   = 128;
constexpr int Hh   = 56;
constexpr int Ww   = 56;
constexpr int OUTC = 128;
constexpr int NTAP = 9;
constexpr int HW   = 3136;
constexpr int NPOS = Bn * HW;      // 25088
constexpr int KDIM = 1152;         // Cc*NTAP

constexpr int PT   = 16;           // K2 positions per block
constexpr int LROW = 1160;         // ushort row stride (2320 B, 16B-aligned)

typedef __attribute__((ext_vector_type(8))) short  short8v;
typedef __attribute__((ext_vector_type(4))) short  short4v;
typedef __attribute__((ext_vector_type(4))) float  float4v;

__device__ __forceinline__ unsigned short f2bf(float f) {
    union { float f; uint32_t u; } v; v.f = f;
    const uint32_t u = v.u;
    return (unsigned short)((u + 0x7fffu + ((u >> 16) & 1u)) >> 16);  // RNE
}
__device__ __forceinline__ float bf2f(unsigned short us) {
    union { uint32_t u; float f; } v; v.u = (uint32_t)us << 16;
    return v.f;
}

// ---------------------------------------------------------------------------
// Prep: (a) cwb: conv weights bf16, k' = n*128 + c
//       (b) owp: offset weights fp32 -> [c][m*9+tap] (contiguous per c)
//       (c) xt : x -> [b][ij][c] bf16 channel-last
// ---------------------------------------------------------------------------
__global__ __launch_bounds__(256) void prep_kernel(
        const float* __restrict__ cw, const float* __restrict__ ow,
        const float* __restrict__ x, unsigned short* __restrict__ cwb,
        float* __restrict__ owp, unsigned short* __restrict__ xt) {
    const int blk = blockIdx.x;
    const int t = threadIdx.x;
    if (blk < 576) {                               // 128*1152 elems
        const int i = blk * 256 + t;
        const int o = i / KDIM, k = i % KDIM;
        const int n = k >> 7, c = k & 127;         // k' = n*128 + c
        cwb[i] = f2bf(cw[o * KDIM + c * NTAP + n]);
        return;
    }
    if (blk < 657) {                               // owp: 128*162 = 20736 elems
        const int i = (blk - 576) * 256 + t;
        const int c = i / 162, r = i % 162;        // r = m*9+tap
        owp[i] = ow[(r / 9) * KDIM + c * NTAP + (r % 9)];
        return;
    }
    // transpose: 392 blocks, 64 pos x 128 ch each
    const int blk2 = blk - 657;
    const int b = blk2 & 7;
    const int ijb = (blk2 >> 3) * 64;
    const int lp = t & 63, cg = t >> 6;
    const float* xb = x + (size_t)b * Cc * HW + ijb + lp;
    unsigned short* xr = xt + ((size_t)b * HW + ijb + lp) * Cc + cg * 32;
#pragma unroll
    for (int c8 = 0; c8 < 4; ++c8) {
        short8v sv;
#pragma unroll
        for (int u = 0; u < 8; ++u)
            sv[u] = (short)f2bf(xb[(size_t)(cg * 32 + c8 * 8 + u) * HW]);
        *(short8v*)(xr + c8 * 8) = sv;
    }
}

// ---------------------------------------------------------------------------
// K1: offset conv + p. FP chain BIT-IDENTICAL to the R4/R5/R6-verified pbuf.
// Weights staged in LDS with b128-aligned rows ([c][mm][12]), two m-passes
// of 9; all lanes read the same LDS address (broadcast, conflict-free).
// x taps via global loads (vmcnt only; no lgkm mixing in the FMA loop).
// red[] overlays the weight buffer after the last pass.
// ---------------------------------------------------------------------------
__global__ __launch_bounds__(512) void offset_p_kernel(
        const float* __restrict__ x, const float* __restrict__ owp,
        const float* __restrict__ ob, float* __restrict__ pbuf) {
    __shared__ float smem[13824];                  // 55.3 KB (w-stage / red union)

    const int t    = threadIdx.x;
    const int lane = t & 63;
    const int g    = __builtin_amdgcn_readfirstlane(t >> 6);   // wave-uniform
    const int blk  = blockIdx.x;
    const int b    = blk & 7;                      // XCD affinity
    const int ijb  = (blk >> 3) * 64;
    const int ij   = ijb + lane;
    const int i    = ij / Ww, j = ij % Ww;
    const float* xb = x + (size_t)b * Cc * HW;

    float acc[18];
#pragma unroll
    for (int m = 0; m < 18; ++m) acc[m] = 0.f;

    for (int pass = 0; pass < 2; ++pass) {
        const int m0 = pass * 9;
        if (pass) __syncthreads();                 // prior pass reads done
        // ---- stage weights for m in [m0, m0+9): smem[c*108 + mm*12 + tap] ----
        for (int e = t; e < 13824; e += 512) {
            const int c = e / 108, r = e % 108, mm = r / 12, tap = r % 12;
            smem[e] = (tap < 9) ? owp[c * 162 + (m0 + mm) * 9 + tap] : 0.f;
        }
        __syncthreads();

        for (int cc = 0; cc < 16; ++cc) {
            const int c = g * 16 + cc;
            const float* xc = xb + (size_t)c * HW;
            float xv[9];
#pragma unroll
            for (int ky = 0; ky < 3; ++ky) {
                const int y = i + ky - 1;
                const bool yv = (unsigned)y < (unsigned)Hh;
#pragma unroll
                for (int kx = 0; kx < 3; ++kx) {
                    const int xx = j + kx - 1;
                    xv[ky * 3 + kx] = (yv && (unsigned)xx < (unsigned)Ww) ? xc[y * Ww + xx] : 0.f;
                }
            }
            const float* wp = &smem[c * 108];      // broadcast LDS reads
#pragma unroll
            for (int mm = 0; mm < 9; ++mm) {
#pragma unroll
                for (int tap = 0; tap < 9; ++tap)
                    acc[m0 + mm] = fmaf(wp[mm * 12 + tap], xv[tap], acc[m0 + mm]);
            }
        }
    }
    __syncthreads();                               // weight reads done

    float* red = smem;                             // overlay: [g][lane*18+m]
#pragma unroll
    for (int m = 0; m < 18; ++m) red[g * 1152 + lane * 18 + m] = acc[m];
    __syncthreads();

    for (int e = t; e < 64 * 18; e += 512) {
        const int lpe = e / 18, m = e % 18;
        float s = 0.f;
#pragma unroll
        for (int gg = 0; gg < 8; ++gg) s += red[gg * 1152 + e];
        s += ob[m];
        const int ije = ijb + lpe;
        const float base = (m < 9) ? (float)(ije / Ww + m / 3)
                                   : (float)(ije % Ww + (m - 9) % 3);
        pbuf[(size_t)(b * 18 + m) * HW + ije] = base + s;
    }
}

// ---------------------------------------------------------------------------
// K2: PT=16, SINGLE staging pass of all 128 channels (k' = n*128+c), then
// one uninterrupted 36-step MFMA K-loop. 2 barriers per block total.
// Grid 1568 -> ~6 blocks/CU of work; LDS 40.6 KB -> 3 resident.
// ---------------------------------------------------------------------------
__global__ __launch_bounds__(256) void deform_mfma_kernel(
        const unsigned short* __restrict__ xt, const unsigned short* __restrict__ cwb,
        const float* __restrict__ pbuf, float* __restrict__ out) {
    __shared__ unsigned short xoffB[PT * LROW];    // 37.1 KB
    __shared__ float4v pgS[PT * NTAP];             // {g2,g3,g0,g1}
    __shared__ int2    poS[PT * NTAP];             // {o2|o3<<16, o0|o1<<16}

    const int t    = threadIdx.x;
    const int lane = t & 63;
    const int mm   = lane & 15, quad = lane >> 4;
    const int wv   = t >> 6;
    const int lp   = t & 15, grp = t >> 4;         // staging: pos, 8-ch group
    const int blk  = blockIdx.x;
    const int b    = blk & 7;                      // XCD affinity
    const int ijb  = (blk >> 3) * PT;
    const unsigned short* xtb = xt + (size_t)b * HW * Cc;

    // ---- params: exact fp32 chain (verified bits), e = n*16 + pos ----
    for (int e = t; e < PT * NTAP; e += 256) {
        const int n = e >> 4, lpe = e & 15;
        const int ij = ijb + lpe;
        const float py = pbuf[(size_t)(b * 18 + n) * HW + ij];
        const float px = pbuf[(size_t)(b * 18 + 9 + n) * HW + ij];
        const float q0y = floorf(py), q0x = floorf(px);
        const float lty = fminf(fmaxf(q0y, 0.f), 57.f);
        const float ltx = fminf(fmaxf(q0x, 0.f), 57.f);
        const float rby = fminf(fmaxf(q0y + 1.f, 0.f), 57.f);
        const float rbx = fminf(fmaxf(q0x + 1.f, 0.f), 57.f);
        const float pyc = fminf(fmaxf(py, 0.f), 57.f);
        const float pxc = fminf(fmaxf(px, 0.f), 57.f);
        float g0 = (1.f - (pyc - lty)) * truncf(1.f - (pxc - ltx));   // lt
        float g1 = (1.f - (rby - pyc)) * truncf(1.f - (rbx - pxc));   // rb
        float g2 = (1.f - (pyc - lty)) * (1.f - (rbx - pxc));         // lb (lty,rbx)
        float g3 = (1.f - (rby - pyc)) * (1.f - (pxc - ltx));         // rt (rby,ltx)
        const int y0 = (int)lty - 1, x0 = (int)ltx - 1;
        const int y1 = (int)rby - 1, x1 = (int)rbx - 1;
        const bool v0y = (unsigned)y0 < (unsigned)Hh, v0x = (unsigned)x0 < (unsigned)Ww;
        const bool v1y = (unsigned)y1 < (unsigned)Hh, v1x = (unsigned)x1 < (unsigned)Ww;
        int o0 = y0 * Ww + x0, o1 = y1 * Ww + x1, o2 = y0 * Ww + x1, o3 = y1 * Ww + x0;
        if (!(v0y && v0x)) { o0 = 0; g0 = 0.f; }
        if (!(v1y && v1x)) { o1 = 0; g1 = 0.f; }
        if (!(v0y && v1x)) { o2 = 0; g2 = 0.f; }
        if (!(v1y && v0x)) { o3 = 0; g3 = 0.f; }
        pgS[e] = (float4v){ g2, g3, g0, g1 };
        poS[e] = make_int2((o2 & 0xffff) | (o3 << 16), (o0 & 0xffff) | (o1 << 16));
    }
    __syncthreads();

    // ---- single staging pass: 9 taps x 4 corners x 8 ch (16B bf16 gathers) ----
#pragma unroll
    for (int n = 0; n < 9; ++n) {
        const float4v G = pgS[n * 16 + lp];
        const int2  O = poS[n * 16 + lp];
        const short8v a2 = *(const short8v*)(xtb + (size_t)(O.x & 0xffff) * Cc + grp * 8);
        const short8v a3 = *(const short8v*)(xtb + (size_t)((O.x >> 16) & 0xffff) * Cc + grp * 8);
        const short8v a0 = *(const short8v*)(xtb + (size_t)(O.y & 0xffff) * Cc + grp * 8);
        const short8v a1 = *(const short8v*)(xtb + (size_t)((O.y >> 16) & 0xffff) * Cc + grp * 8);
        short8v sv;
#pragma unroll
        for (int u = 0; u < 8; ++u) {
            float v = G.x * bf2f((unsigned short)a2[u]);
            v = fmaf(G.y, bf2f((unsigned short)a3[u]), v);
            v = fmaf(G.z, bf2f((unsigned short)a0[u]), v);
            v = fmaf(G.w, bf2f((unsigned short)a1[u]), v);
            sv[u] = (short)f2bf(v);
        }
        *(short8v*)&xoffB[lp * LROW + n * Cc + grp * 8] = sv;       // 16B-aligned
    }
    __syncthreads();

    // ---- MFMA: one 36-step K-loop, A via ds_read_b128, B from L2 ----
    float4v acc0 = {0.f, 0.f, 0.f, 0.f}, acc1 = {0.f, 0.f, 0.f, 0.f};
    const unsigned short* bw0 = cwb + (size_t)(wv * 32 + mm) * KDIM + quad * 8;
    const unsigned short* bw1 = bw0 + 16 * KDIM;
    const unsigned short* ap0 = &xoffB[mm * LROW + quad * 8];
#pragma unroll 4
    for (int ks = 0; ks < KDIM / 32; ++ks) {
        const int kl = ks * 32;
        const short8v a  = *(const short8v*)(ap0 + kl);
        const short8v b0 = *(const short8v*)(bw0 + kl);
        const short8v b1 = *(const short8v*)(bw1 + kl);
        acc0 = __builtin_amdgcn_mfma_f32_16x16x32_bf16(a, b0, acc0, 0, 0, 0);
        acc1 = __builtin_amdgcn_mfma_f32_16x16x32_bf16(a, b1, acc1, 0, 0, 0);
    }

    // ---- epilogue (D layout verified R2/R4/R5) ----
    float* ob0 = out + (size_t)(b * OUTC + wv * 32 + mm) * HW + ijb + quad * 4;
    *(float4v*)ob0 = acc0;
    *(float4v*)(ob0 + (size_t)16 * HW) = acc1;
}

}  // namespace

extern "C" void kernel_launch(void* const* d_in, const int* in_sizes, int n_in,
                              void* d_out, int out_size, void* d_ws, size_t ws_size,
                              hipStream_t stream) {
    const float* x  = (const float*)d_in[0];   // (8,128,56,56)
    const float* ow = (const float*)d_in[1];   // (18,128,3,3)
    const float* ob = (const float*)d_in[2];   // (18,)
    const float* cw = (const float*)d_in[3];   // (128,128,3,3)
    float* out = (float*)d_out;                // (8,128,56,56)

    char* wsp = (char*)d_ws;
    float* pbuf = (float*)wsp;                                     // 1,806,336 B
    unsigned short* cwb = (unsigned short*)(wsp + 1806336);        //   294,912 B
    float* owp = (float*)(wsp + 1806336 + 294912);                 //    82,944 B
    unsigned short* xt = (unsigned short*)(wsp + 1806336 + 294912 + 82944);  // 6.42 MB

    prep_kernel<<<576 + 81 + 392, 256, 0, stream>>>(cw, ow, x, cwb, owp, xt);
    offset_p_kernel<<<NPOS / 64, 512, 0, stream>>>(x, owp, ob, pbuf);
    deform_mfma_kernel<<<NPOS / PT, 256, 0, stream>>>(xt, cwb, pbuf, out);
}

// Round 8
// 183.800 us; speedup vs baseline: 1.2835x; 1.2835x over previous
//
#include <hip/hip_runtime.h>
#include <cstdint>
#include <cstddef>

namespace {

constexpr int Bn   = 8;
constexpr int Cc   = 128;
constexpr int Hh   = 56;
constexpr int Ww   = 56;
constexpr int OUTC = 128;
constexpr int NTAP = 9;
constexpr int HW   = 3136;
constexpr int NPOS = Bn * HW;      // 25088
constexpr int KDIM = 1152;         // Cc*NTAP

constexpr int PT   = 32;           // K2 positions per block
constexpr int CCH  = 64;           // K2 channels per chunk (2 chunks)
constexpr int KC   = CCH * NTAP;   // 576
constexpr int LROW = 584;          // ushort row stride (1168B, 16B-aligned)

typedef __attribute__((ext_vector_type(8))) short  short8v;
typedef __attribute__((ext_vector_type(4))) short  short4v;
typedef __attribute__((ext_vector_type(4))) float  float4v;

__device__ __forceinline__ unsigned short f2bf(float f) {
    union { float f; uint32_t u; } v; v.f = f;
    const uint32_t u = v.u;
    return (unsigned short)((u + 0x7fffu + ((u >> 16) & 1u)) >> 16);  // RNE
}
__device__ __forceinline__ float bf2f(unsigned short us) {
    union { uint32_t u; float f; } v; v.u = (uint32_t)us << 16;
    return v.f;
}

// ---------------------------------------------------------------------------
// Prep (R5 layout): (a) cwb bf16, k' = cc*576 + n*64 + cl
//                   (b) owp fp32 [c][m*9+tap]
//                   (c) xt bf16 channel-last [b][ij][c]
// ---------------------------------------------------------------------------
__global__ __launch_bounds__(256) void prep_kernel(
        const float* __restrict__ cw, const float* __restrict__ ow,
        const float* __restrict__ x, unsigned short* __restrict__ cwb,
        float* __restrict__ owp, unsigned short* __restrict__ xt) {
    const int blk = blockIdx.x;
    const int t = threadIdx.x;
    if (blk < 576) {                               // weights: 128*1152 elems
        const int i = blk * 256 + t;
        const int o = i / KDIM, k = i % KDIM;
        const int cc = k / KC, r = k % KC, n = r >> 6, cl = r & 63;
        cwb[i] = f2bf(cw[o * KDIM + (cc * CCH + cl) * NTAP + n]);
        return;
    }
    if (blk < 657) {                               // owp: 128*162 = 20736 elems
        const int i = (blk - 576) * 256 + t;
        const int c = i / 162, r = i % 162;        // r = m*9+tap
        owp[i] = ow[(r / 9) * KDIM + c * NTAP + (r % 9)];
        return;
    }
    // transpose: 392 blocks, 64 pos x 128 ch each
    const int blk2 = blk - 657;
    const int b = blk2 & 7;
    const int ijb = (blk2 >> 3) * 64;
    const int lp = t & 63, cg = t >> 6;
    const float* xb = x + (size_t)b * Cc * HW + ijb + lp;
    unsigned short* xr = xt + ((size_t)b * HW + ijb + lp) * Cc + cg * 32;
#pragma unroll
    for (int c8 = 0; c8 < 4; ++c8) {
        short8v sv;
#pragma unroll
        for (int u = 0; u < 8; ++u)
            sv[u] = (short)f2bf(xb[(size_t)(cg * 32 + c8 * 8 + u) * HW]);
        *(short8v*)(xr + c8 * 8) = sv;
    }
}

// ---------------------------------------------------------------------------
// K1a: offset-conv chunk partials. Grid 784 = 392 pos-groups x 2 c-chunks
// (64c). Block 256 = 64 pos x 4 wave-uniform 16-c slices. Per-slice fmaf
// chain BIT-IDENTICAL to verified pbuf; in-block tree (r0+r1)+(r2+r3).
// No weight-per-FMA load storms bigger than one contiguous s_load run/cc.
// ---------------------------------------------------------------------------
__global__ __launch_bounds__(256) void offset_part_kernel(
        const float* __restrict__ x, const float* __restrict__ owp,
        float* __restrict__ partial) {
    __shared__ float red[4][64 * 18];              // 18.4 KB

    const int t    = threadIdx.x;
    const int lane = t & 63;
    const int sq   = __builtin_amdgcn_readfirstlane(t >> 6);   // wave-uniform slice
    const int blk  = blockIdx.x;
    const int chunk = blk & 1;
    const int pgi  = blk >> 1;
    const int b    = pgi & 7;                      // XCD affinity
    const int ijb  = (pgi >> 3) * 64;
    const int ij   = ijb + lane;
    const int i    = ij / Ww, j = ij % Ww;
    const float* xb = x + (size_t)b * Cc * HW;

    float acc[18];
#pragma unroll
    for (int m = 0; m < 18; ++m) acc[m] = 0.f;

    const int c0 = chunk * 64 + sq * 16;
    for (int cc = 0; cc < 16; ++cc) {
        const int c = c0 + cc;
        const float* xc = xb + (size_t)c * HW;
        float xv[9];
#pragma unroll
        for (int ky = 0; ky < 3; ++ky) {
            const int y = i + ky - 1;
            const bool yv = (unsigned)y < (unsigned)Hh;
#pragma unroll
            for (int kx = 0; kx < 3; ++kx) {
                const int xx = j + kx - 1;
                xv[ky * 3 + kx] = (yv && (unsigned)xx < (unsigned)Ww) ? xc[y * Ww + xx] : 0.f;
            }
        }
        const float* wp = owp + c * 162;           // wave-uniform, contiguous
#pragma unroll
        for (int m = 0; m < 18; ++m) {
#pragma unroll
            for (int tap = 0; tap < 9; ++tap)
                acc[m] = fmaf(wp[m * 9 + tap], xv[tap], acc[m]);
        }
    }

#pragma unroll
    for (int m = 0; m < 18; ++m) red[sq][lane * 18 + m] = acc[m];
    __syncthreads();

    float* pout = partial + (size_t)chunk * Bn * 18 * HW;
    for (int e = t; e < 64 * 18; e += 256) {
        const int lpe = e / 18, m = e % 18;
        const float s01 = red[0][e] + red[1][e];
        const float s23 = red[2][e] + red[3][e];
        pout[(size_t)(b * 18 + m) * HW + ijb + lpe] = s01 + s23;
    }
}

// ---------------------------------------------------------------------------
// K1b: pbuf = (P0 + P1) + bias + base.  float4 over ij.
// ---------------------------------------------------------------------------
__global__ __launch_bounds__(256) void offset_combine_kernel(
        const float* __restrict__ partial, const float* __restrict__ ob,
        float* __restrict__ pbuf) {
    const int idx = blockIdx.x * 256 + threadIdx.x;      // (bm, ij4)
    if (idx >= Bn * 18 * (HW / 4)) return;
    const int bm = idx / (HW / 4), ij0 = (idx % (HW / 4)) * 4;
    const int m = bm % 18;
    const float bias = ob[m];
    const float4v P0 = *(const float4v*)(partial + (size_t)bm * HW + ij0);
    const float4v P1 = *(const float4v*)(partial + (size_t)(Bn * 18 + bm) * HW + ij0);
    float4v r;
#pragma unroll
    for (int u = 0; u < 4; ++u) {
        const int ije = ij0 + u;
        const float base = (m < 9) ? (float)(ije / Ww + m / 3)
                                   : (float)(ije % Ww + (m - 9) % 3);
        r[u] = base + ((P0[u] + P1[u]) + bias);
    }
    *(float4v*)(pbuf + (size_t)bm * HW + ij0) = r;
}

// ---------------------------------------------------------------------------
// K2: EXACT R5 revert — branchless 4-corner sampling from channel-last bf16
// xt + MFMA GEMM, 2 chunks of 64 ch, params in LDS. 67 us measured.
// ---------------------------------------------------------------------------
__global__ __launch_bounds__(256, 3) void deform_mfma_kernel(
        const unsigned short* __restrict__ xt, const unsigned short* __restrict__ cwb,
        const float* __restrict__ pbuf, float* __restrict__ out) {
    __shared__ unsigned short xoffB[PT * LROW];    // 36.5 KB
    __shared__ float4v pgS[PT * NTAP];             // {g2,g3,g0,g1}  4.6 KB
    __shared__ int2    poS[PT * NTAP];             // {o2|o3<<16, o0|o1<<16}

    const int t    = threadIdx.x;
    const int lane = t & 63;
    const int mm   = lane & 15, quad = lane >> 4;
    const int wv   = t >> 6;
    const int lp   = t & 31, grp = t >> 5;         // staging: pos, 8-ch group
    const int blk  = blockIdx.x;
    const int b    = blk & 7;                      // XCD affinity
    const int ijb  = (blk >> 3) * PT;
    const unsigned short* xtb = xt + (size_t)b * HW * Cc;

    // ---- params: exact fp32, once per (pos,tap); e = n*32 + pos ----
    for (int e = t; e < PT * NTAP; e += 256) {
        const int n = e >> 5, lpe = e & 31;
        const int ij = ijb + lpe;
        const float py = pbuf[(size_t)(b * 18 + n) * HW + ij];
        const float px = pbuf[(size_t)(b * 18 + 9 + n) * HW + ij];
        const float q0y = floorf(py), q0x = floorf(px);
        const float lty = fminf(fmaxf(q0y, 0.f), 57.f);
        const float ltx = fminf(fmaxf(q0x, 0.f), 57.f);
        const float rby = fminf(fmaxf(q0y + 1.f, 0.f), 57.f);
        const float rbx = fminf(fmaxf(q0x + 1.f, 0.f), 57.f);
        const float pyc = fminf(fmaxf(py, 0.f), 57.f);
        const float pxc = fminf(fmaxf(px, 0.f), 57.f);
        float g0 = (1.f - (pyc - lty)) * truncf(1.f - (pxc - ltx));   // lt
        float g1 = (1.f - (rby - pyc)) * truncf(1.f - (rbx - pxc));   // rb
        float g2 = (1.f - (pyc - lty)) * (1.f - (rbx - pxc));         // lb (lty,rbx)
        float g3 = (1.f - (rby - pyc)) * (1.f - (pxc - ltx));         // rt (rby,ltx)
        const int y0 = (int)lty - 1, x0 = (int)ltx - 1;
        const int y1 = (int)rby - 1, x1 = (int)rbx - 1;
        const bool v0y = (unsigned)y0 < (unsigned)Hh, v0x = (unsigned)x0 < (unsigned)Ww;
        const bool v1y = (unsigned)y1 < (unsigned)Hh, v1x = (unsigned)x1 < (unsigned)Ww;
        int o0 = y0 * Ww + x0, o1 = y1 * Ww + x1, o2 = y0 * Ww + x1, o3 = y1 * Ww + x0;
        if (!(v0y && v0x)) { o0 = 0; g0 = 0.f; }
        if (!(v1y && v1x)) { o1 = 0; g1 = 0.f; }
        if (!(v0y && v1x)) { o2 = 0; g2 = 0.f; }
        if (!(v1y && v0x)) { o3 = 0; g3 = 0.f; }
        pgS[e] = (float4v){ g2, g3, g0, g1 };
        poS[e] = make_int2((o2 & 0xffff) | (o3 << 16), (o0 & 0xffff) | (o1 << 16));
    }

    float4v acc[2][2] = { { {0.f,0.f,0.f,0.f}, {0.f,0.f,0.f,0.f} },
                          { {0.f,0.f,0.f,0.f}, {0.f,0.f,0.f,0.f} } };
    __syncthreads();

    for (int cc = 0; cc < 2; ++cc) {
        if (cc) __syncthreads();
        // ---- branchless staging: 9 taps x (4 gathers of 8ch) ----
        const int cbase = cc * CCH + grp * 8;
#pragma unroll
        for (int n = 0; n < 9; ++n) {
            const float4v G = pgS[n * 32 + lp];
            const int2  O = poS[n * 32 + lp];
            const short8v a2 = *(const short8v*)(xtb + (size_t)(O.x & 0xffff) * Cc + cbase);
            const short8v a3 = *(const short8v*)(xtb + (size_t)((O.x >> 16) & 0xffff) * Cc + cbase);
            const short8v a0 = *(const short8v*)(xtb + (size_t)(O.y & 0xffff) * Cc + cbase);
            const short8v a1 = *(const short8v*)(xtb + (size_t)((O.y >> 16) & 0xffff) * Cc + cbase);
            short8v sv;
#pragma unroll
            for (int u = 0; u < 8; ++u) {
                float v = G.x * bf2f((unsigned short)a2[u]);
                v = fmaf(G.y, bf2f((unsigned short)a3[u]), v);
                v = fmaf(G.z, bf2f((unsigned short)a0[u]), v);
                v = fmaf(G.w, bf2f((unsigned short)a1[u]), v);
                sv[u] = (short)f2bf(v);
            }
            *(short8v*)&xoffB[lp * LROW + n * CCH + grp * 8] = sv;
        }
        __syncthreads();

        // ---- MFMA GEMM: 18 ks-steps, B straight from L2 ----
        const unsigned short* bw0 = cwb + (size_t)(wv * 32 + mm) * KDIM + cc * KC;
        const unsigned short* bw1 = bw0 + 16 * KDIM;
        const unsigned short* ap0 = &xoffB[mm * LROW + quad * 8];
#pragma unroll 3
        for (int ks = 0; ks < KC / 32; ++ks) {
            const int kl = ks * 32;
            const short8v b0 = *(const short8v*)(bw0 + kl + quad * 8);
            const short8v b1 = *(const short8v*)(bw1 + kl + quad * 8);
#pragma unroll
            for (int pt = 0; pt < 2; ++pt) {
                const unsigned short* ap = ap0 + pt * 16 * LROW + kl;
                const short4v alo = *(const short4v*)ap;
                const short4v ahi = *(const short4v*)(ap + 4);
                const short8v a = __builtin_shufflevector(alo, ahi, 0, 1, 2, 3, 4, 5, 6, 7);
                acc[pt][0] = __builtin_amdgcn_mfma_f32_16x16x32_bf16(a, b0, acc[pt][0], 0, 0, 0);
                acc[pt][1] = __builtin_amdgcn_mfma_f32_16x16x32_bf16(a, b1, acc[pt][1], 0, 0, 0);
            }
        }
    }

    // ---- epilogue (layout verified R2/R4/R5) ----
    float* ob0 = out + (size_t)(b * OUTC + wv * 32 + mm) * HW + ijb + quad * 4;
#pragma unroll
    for (int pt = 0; pt < 2; ++pt) {
        *(float4v*)(ob0 + pt * 16) = acc[pt][0];
        *(float4v*)(ob0 + (size_t)16 * HW + pt * 16) = acc[pt][1];
    }
}

}  // namespace

extern "C" void kernel_launch(void* const* d_in, const int* in_sizes, int n_in,
                              void* d_out, int out_size, void* d_ws, size_t ws_size,
                              hipStream_t stream) {
    const float* x  = (const float*)d_in[0];   // (8,128,56,56)
    const float* ow = (const float*)d_in[1];   // (18,128,3,3)
    const float* ob = (const float*)d_in[2];   // (18,)
    const float* cw = (const float*)d_in[3];   // (128,128,3,3)
    float* out = (float*)d_out;                // (8,128,56,56)

    char* wsp = (char*)d_ws;
    float* pbuf = (float*)wsp;                                  //  1,806,336 B
    unsigned short* cwb = (unsigned short*)(wsp + 1806336);     //    294,912 B
    float* owp = (float*)(wsp + 2101248);                       //     82,944 B
    unsigned short* xt = (unsigned short*)(wsp + 2184192);      //  6,422,528 B
    float* partial = (float*)(wsp + 8606720);                   //  3,612,672 B (2 chunks)

    prep_kernel<<<576 + 81 + 392, 256, 0, stream>>>(cw, ow, x, cwb, owp, xt);
    offset_part_kernel<<<784, 256, 0, stream>>>(x, owp, partial);
    offset_combine_kernel<<<(Bn * 18 * (HW / 4) + 255) / 256, 256, 0, stream>>>(partial, ob, pbuf);
    deform_mfma_kernel<<<NPOS / PT, 256, 0, stream>>>(xt, cwb, pbuf, out);
}

// Round 9
// 165.069 us; speedup vs baseline: 1.4291x; 1.1135x over previous
//
#include <hip/hip_runtime.h>
#include <cstdint>
#include <cstddef>

namespace {

constexpr int Bn   = 8;
constexpr int Cc   = 128;
constexpr int Hh   = 56;
constexpr int Ww   = 56;
constexpr int OUTC = 128;
constexpr int NTAP = 9;
constexpr int HW   = 3136;
constexpr int NPOS = Bn * HW;      // 25088
constexpr int KDIM = 1152;         // Cc*NTAP
constexpr int CH   = Bn * 18 * HW; // partial chunk stride (451584 floats)

constexpr int PT   = 32;           // K2 positions per block
constexpr int CCH  = 64;           // K2 channels per chunk (2 chunks)
constexpr int KC   = CCH * NTAP;   // 576
constexpr int LROW = 584;          // ushort row stride (1168B, 16B-aligned)

typedef __attribute__((ext_vector_type(8))) short  short8v;
typedef __attribute__((ext_vector_type(4))) short  short4v;
typedef __attribute__((ext_vector_type(4))) float  float4v;

__device__ __forceinline__ unsigned short f2bf(float f) {
    union { float f; uint32_t u; } v; v.f = f;
    const uint32_t u = v.u;
    return (unsigned short)((u + 0x7fffu + ((u >> 16) & 1u)) >> 16);  // RNE
}
__device__ __forceinline__ float bf2f(unsigned short us) {
    union { uint32_t u; float f; } v; v.u = (uint32_t)us << 16;
    return v.f;
}

// ---------------------------------------------------------------------------
// Prep (unchanged from R8): (a) cwb bf16, k' = cc*576 + n*64 + cl
//                           (b) owp fp32 [c][m*9+tap]
//                           (c) xt bf16 channel-last [b][ij][c]
// ---------------------------------------------------------------------------
__global__ __launch_bounds__(256) void prep_kernel(
        const float* __restrict__ cw, const float* __restrict__ ow,
        const float* __restrict__ x, unsigned short* __restrict__ cwb,
        float* __restrict__ owp, unsigned short* __restrict__ xt) {
    const int blk = blockIdx.x;
    const int t = threadIdx.x;
    if (blk < 576) {                               // weights: 128*1152 elems
        const int i = blk * 256 + t;
        const int o = i / KDIM, k = i % KDIM;
        const int cc = k / KC, r = k % KC, n = r >> 6, cl = r & 63;
        cwb[i] = f2bf(cw[o * KDIM + (cc * CCH + cl) * NTAP + n]);
        return;
    }
    if (blk < 657) {                               // owp: 128*162 = 20736 elems
        const int i = (blk - 576) * 256 + t;
        const int c = i / 162, r = i % 162;        // r = m*9+tap
        owp[i] = ow[(r / 9) * KDIM + c * NTAP + (r % 9)];
        return;
    }
    // transpose: 392 blocks, 64 pos x 128 ch each
    const int blk2 = blk - 657;
    const int b = blk2 & 7;
    const int ijb = (blk2 >> 3) * 64;
    const int lp = t & 63, cg = t >> 6;
    const float* xb = x + (size_t)b * Cc * HW + ijb + lp;
    unsigned short* xr = xt + ((size_t)b * HW + ijb + lp) * Cc + cg * 32;
#pragma unroll
    for (int c8 = 0; c8 < 4; ++c8) {
        short8v sv;
#pragma unroll
        for (int u = 0; u < 8; ++u)
            sv[u] = (short)f2bf(xb[(size_t)(cg * 32 + c8 * 8 + u) * HW]);
        *(short8v*)(xr + c8 * 8) = sv;
    }
}

// ---------------------------------------------------------------------------
// K1a: offset-conv chunk partials. 4 chunks of 32c -> 1568 blocks -> 6272
// waves = 6.1/SIMD (double R8's 3.06 — the occupancy lever). Block 256 =
// 64 pos x 4 wave-uniform 8-c slices; per-slice fmaf tap chain preserved;
// in-block tree (r0+r1)+(r2+r3) per chunk.
// ---------------------------------------------------------------------------
__global__ __launch_bounds__(256) void offset_part_kernel(
        const float* __restrict__ x, const float* __restrict__ owp,
        float* __restrict__ partial) {
    __shared__ float red[4][64 * 18];              // 18.4 KB

    const int t    = threadIdx.x;
    const int lane = t & 63;
    const int sq   = __builtin_amdgcn_readfirstlane(t >> 6);   // wave-uniform slice
    const int blk  = blockIdx.x;
    const int chunk = blk & 3;                     // 32-c chunk
    const int pgi  = blk >> 2;
    const int b    = pgi & 7;                      // XCD affinity
    const int ijb  = (pgi >> 3) * 64;
    const int ij   = ijb + lane;
    const int i    = ij / Ww, j = ij % Ww;
    const float* xb = x + (size_t)b * Cc * HW;

    float acc[18];
#pragma unroll
    for (int m = 0; m < 18; ++m) acc[m] = 0.f;

    const int c0 = chunk * 32 + sq * 8;
    for (int cc = 0; cc < 8; ++cc) {
        const int c = c0 + cc;
        const float* xc = xb + (size_t)c * HW;
        float xv[9];
#pragma unroll
        for (int ky = 0; ky < 3; ++ky) {
            const int y = i + ky - 1;
            const bool yv = (unsigned)y < (unsigned)Hh;
#pragma unroll
            for (int kx = 0; kx < 3; ++kx) {
                const int xx = j + kx - 1;
                xv[ky * 3 + kx] = (yv && (unsigned)xx < (unsigned)Ww) ? xc[y * Ww + xx] : 0.f;
            }
        }
        const float* wp = owp + c * 162;           // wave-uniform, contiguous
#pragma unroll
        for (int m = 0; m < 18; ++m) {
#pragma unroll
            for (int tap = 0; tap < 9; ++tap)
                acc[m] = fmaf(wp[m * 9 + tap], xv[tap], acc[m]);
        }
    }

#pragma unroll
    for (int m = 0; m < 18; ++m) red[sq][lane * 18 + m] = acc[m];
    __syncthreads();

    float* pout = partial + (size_t)chunk * CH;
    for (int e = t; e < 64 * 18; e += 256) {
        const int lpe = e / 18, m = e % 18;
        const float s01 = red[0][e] + red[1][e];
        const float s23 = red[2][e] + red[3][e];
        pout[(size_t)(b * 18 + m) * HW + ijb + lpe] = s01 + s23;
    }
}

// ---------------------------------------------------------------------------
// K2: R8's proven kernel; ONLY change: params phase combines the 4 chunk
// partials inline (p = base + (((P0+P1)+(P2+P3)) + bias)) — K1b eliminated.
// ---------------------------------------------------------------------------
__global__ __launch_bounds__(256, 3) void deform_mfma_kernel(
        const unsigned short* __restrict__ xt, const unsigned short* __restrict__ cwb,
        const float* __restrict__ partial, const float* __restrict__ ob,
        float* __restrict__ out) {
    __shared__ unsigned short xoffB[PT * LROW];    // 36.5 KB
    __shared__ float4v pgS[PT * NTAP];             // {g2,g3,g0,g1}  4.6 KB
    __shared__ int2    poS[PT * NTAP];             // {o2|o3<<16, o0|o1<<16}

    const int t    = threadIdx.x;
    const int lane = t & 63;
    const int mm   = lane & 15, quad = lane >> 4;
    const int wv   = t >> 6;
    const int lp   = t & 31, grp = t >> 5;         // staging: pos, 8-ch group
    const int blk  = blockIdx.x;
    const int b    = blk & 7;                      // XCD affinity
    const int ijb  = (blk >> 3) * PT;
    const unsigned short* xtb = xt + (size_t)b * HW * Cc;

    // ---- params: inline 4-partial combine, then exact fp32 chain ----
    for (int e = t; e < PT * NTAP; e += 256) {
        const int n = e >> 5, lpe = e & 31;
        const int ij = ijb + lpe;
        const size_t iy = (size_t)(b * 18 + n) * HW + ij;
        const size_t ix = (size_t)(b * 18 + 9 + n) * HW + ij;
        float sy = (partial[iy] + partial[CH + iy]) + (partial[2 * CH + iy] + partial[3 * CH + iy]);
        float sx = (partial[ix] + partial[CH + ix]) + (partial[2 * CH + ix] + partial[3 * CH + ix]);
        sy = sy + ob[n];
        sx = sx + ob[9 + n];
        const float py = (float)(ij / Ww + n / 3) + sy;
        const float px = (float)(ij % Ww + n % 3) + sx;
        const float q0y = floorf(py), q0x = floorf(px);
        const float lty = fminf(fmaxf(q0y, 0.f), 57.f);
        const float ltx = fminf(fmaxf(q0x, 0.f), 57.f);
        const float rby = fminf(fmaxf(q0y + 1.f, 0.f), 57.f);
        const float rbx = fminf(fmaxf(q0x + 1.f, 0.f), 57.f);
        const float pyc = fminf(fmaxf(py, 0.f), 57.f);
        const float pxc = fminf(fmaxf(px, 0.f), 57.f);
        float g0 = (1.f - (pyc - lty)) * truncf(1.f - (pxc - ltx));   // lt
        float g1 = (1.f - (rby - pyc)) * truncf(1.f - (rbx - pxc));   // rb
        float g2 = (1.f - (pyc - lty)) * (1.f - (rbx - pxc));         // lb (lty,rbx)
        float g3 = (1.f - (rby - pyc)) * (1.f - (pxc - ltx));         // rt (rby,ltx)
        const int y0 = (int)lty - 1, x0 = (int)ltx - 1;
        const int y1 = (int)rby - 1, x1 = (int)rbx - 1;
        const bool v0y = (unsigned)y0 < (unsigned)Hh, v0x = (unsigned)x0 < (unsigned)Ww;
        const bool v1y = (unsigned)y1 < (unsigned)Hh, v1x = (unsigned)x1 < (unsigned)Ww;
        int o0 = y0 * Ww + x0, o1 = y1 * Ww + x1, o2 = y0 * Ww + x1, o3 = y1 * Ww + x0;
        if (!(v0y && v0x)) { o0 = 0; g0 = 0.f; }
        if (!(v1y && v1x)) { o1 = 0; g1 = 0.f; }
        if (!(v0y && v1x)) { o2 = 0; g2 = 0.f; }
        if (!(v1y && v0x)) { o3 = 0; g3 = 0.f; }
        pgS[e] = (float4v){ g2, g3, g0, g1 };
        poS[e] = make_int2((o2 & 0xffff) | (o3 << 16), (o0 & 0xffff) | (o1 << 16));
    }

    float4v acc[2][2] = { { {0.f,0.f,0.f,0.f}, {0.f,0.f,0.f,0.f} },
                          { {0.f,0.f,0.f,0.f}, {0.f,0.f,0.f,0.f} } };
    __syncthreads();

    for (int cc = 0; cc < 2; ++cc) {
        if (cc) __syncthreads();
        // ---- branchless staging: 9 taps x (4 gathers of 8ch) ----
        const int cbase = cc * CCH + grp * 8;
#pragma unroll
        for (int n = 0; n < 9; ++n) {
            const float4v G = pgS[n * 32 + lp];
            const int2  O = poS[n * 32 + lp];
            const short8v a2 = *(const short8v*)(xtb + (size_t)(O.x & 0xffff) * Cc + cbase);
            const short8v a3 = *(const short8v*)(xtb + (size_t)((O.x >> 16) & 0xffff) * Cc + cbase);
            const short8v a0 = *(const short8v*)(xtb + (size_t)(O.y & 0xffff) * Cc + cbase);
            const short8v a1 = *(const short8v*)(xtb + (size_t)((O.y >> 16) & 0xffff) * Cc + cbase);
            short8v sv;
#pragma unroll
            for (int u = 0; u < 8; ++u) {
                float v = G.x * bf2f((unsigned short)a2[u]);
                v = fmaf(G.y, bf2f((unsigned short)a3[u]), v);
                v = fmaf(G.z, bf2f((unsigned short)a0[u]), v);
                v = fmaf(G.w, bf2f((unsigned short)a1[u]), v);
                sv[u] = (short)f2bf(v);
            }
            *(short8v*)&xoffB[lp * LROW + n * CCH + grp * 8] = sv;
        }
        __syncthreads();

        // ---- MFMA GEMM: 18 ks-steps, B straight from L2 ----
        const unsigned short* bw0 = cwb + (size_t)(wv * 32 + mm) * KDIM + cc * KC;
        const unsigned short* bw1 = bw0 + 16 * KDIM;
        const unsigned short* ap0 = &xoffB[mm * LROW + quad * 8];
#pragma unroll 3
        for (int ks = 0; ks < KC / 32; ++ks) {
            const int kl = ks * 32;
            const short8v b0 = *(const short8v*)(bw0 + kl + quad * 8);
            const short8v b1 = *(const short8v*)(bw1 + kl + quad * 8);
#pragma unroll
            for (int pt = 0; pt < 2; ++pt) {
                const unsigned short* ap = ap0 + pt * 16 * LROW + kl;
                const short4v alo = *(const short4v*)ap;
                const short4v ahi = *(const short4v*)(ap + 4);
                const short8v a = __builtin_shufflevector(alo, ahi, 0, 1, 2, 3, 4, 5, 6, 7);
                acc[pt][0] = __builtin_amdgcn_mfma_f32_16x16x32_bf16(a, b0, acc[pt][0], 0, 0, 0);
                acc[pt][1] = __builtin_amdgcn_mfma_f32_16x16x32_bf16(a, b1, acc[pt][1], 0, 0, 0);
            }
        }
    }

    // ---- epilogue (layout verified R2/R4/R5) ----
    float* ob0 = out + (size_t)(b * OUTC + wv * 32 + mm) * HW + ijb + quad * 4;
#pragma unroll
    for (int pt = 0; pt < 2; ++pt) {
        *(float4v*)(ob0 + pt * 16) = acc[pt][0];
        *(float4v*)(ob0 + (size_t)16 * HW + pt * 16) = acc[pt][1];
    }
}

}  // namespace

extern "C" void kernel_launch(void* const* d_in, const int* in_sizes, int n_in,
                              void* d_out, int out_size, void* d_ws, size_t ws_size,
                              hipStream_t stream) {
    const float* x  = (const float*)d_in[0];   // (8,128,56,56)
    const float* ow = (const float*)d_in[1];   // (18,128,3,3)
    const float* ob = (const float*)d_in[2];   // (18,)
    const float* cw = (const float*)d_in[3];   // (128,128,3,3)
    float* out = (float*)d_out;                // (8,128,56,56)

    char* wsp = (char*)d_ws;
    unsigned short* cwb = (unsigned short*)wsp;                 //    294,912 B
    float* owp = (float*)(wsp + 294912);                        //     82,944 B
    unsigned short* xt = (unsigned short*)(wsp + 377856);       //  6,422,528 B
    float* partial = (float*)(wsp + 6800384);                   //  7,225,344 B (4 chunks)
                                                                // total 14.03 MB

    prep_kernel<<<576 + 81 + 392, 256, 0, stream>>>(cw, ow, x, cwb, owp, xt);
    offset_part_kernel<<<1568, 256, 0, stream>>>(x, owp, partial);
    deform_mfma_kernel<<<NPOS / PT, 256, 0, stream>>>(xt, cwb, partial, ob, out);
}